// Round 1
// baseline (1519.783 us; speedup 1.0000x reference)
//
#include <hip/hip_runtime.h>
#include <math.h>

#define HH 19
#define NB 1024
#define TT 2048

__device__ __forceinline__ float rl(float v, int l) {
  return __uint_as_float(__builtin_amdgcn_readlane(__float_as_uint(v), l));
}

__global__ __launch_bounds__(64, 1) void gru_fused_kernel(
    const float* __restrict__ x, const float* __restrict__ Wih,
    const float* __restrict__ Whh, const float* __restrict__ bih,
    const float* __restrict__ bhh, const float* __restrict__ Wout,
    const float* __restrict__ bout, float* __restrict__ out)
{
  const int b = blockIdx.x;
  const int lane = threadIdx.x;
  const int g = lane < 57 ? lane : 56;

  // weight rows resident in VGPRs for the whole kernel
  float wih[HH], whh[HH], wout[HH];
#pragma unroll
  for (int k = 0; k < HH; ++k) {
    wih[k]  = Wih[g * HH + k];
    whh[k]  = Whh[g * HH + k];
    wout[k] = Wout[k];
  }
  const float bi = bih[g];
  const float bh = bhh[g];
  const float bo = bout[0];

  float h = 0.0f;      // lane i<19 holds h_i
  float sh[HH];        // wave-uniform copy of h (SGPRs via readlane)
#pragma unroll
  for (int k = 0; k < HH; ++k) sh[k] = 0.0f;

  // bpermute source lanes (precomputed, constant per lane)
  const int srcr = (lane >= 38 && lane < 57) ? (lane - 38) : lane; // r_i -> n lane
  const int il   = lane < HH ? lane : HH - 1;
  const int srcz = il + 19;
  const int srcn = il + 38;

  // x[t=0, b, :] — wave-uniform address, broadcast load
  float xv[HH];
  {
    const float* xr = x + (size_t)b * HH;
#pragma unroll
    for (int k = 0; k < HH; ++k) xv[k] = xr[k];
  }

  for (int t = 0; t < TT; ++t) {
    // prefetch next step's x (independent of recurrence chain)
    float xn[HH];
    const bool more = (t + 1 < TT);
    if (more) {
      const float* xr = x + ((size_t)(t + 1) * NB + b) * HH;
#pragma unroll
      for (int k = 0; k < HH; ++k) xn[k] = xr[k];
    }

    // gate dots: x-part (VGPR x VGPR) and h-part (SGPR x VGPR), 2 acc trees each
    float ax0 = 0.f, ax1 = 0.f, ah0 = 0.f, ah1 = 0.f;
#pragma unroll
    for (int k = 0; k < HH; k += 2) {
      ax0 = fmaf(xv[k], wih[k], ax0);
      ah0 = fmaf(sh[k], whh[k], ah0);
    }
#pragma unroll
    for (int k = 1; k < HH; k += 2) {
      ax1 = fmaf(xv[k], wih[k], ax1);
      ah1 = fmaf(sh[k], whh[k], ah1);
    }
    const float prex = ax0 + ax1 + bi;   // x·Wih[g] + bih[g]
    const float preh = ah0 + ah1 + bh;   // h·Whh[g] + bhh[g]

    // sigmoid (meaningful for r/z lanes)
    const float s   = prex + preh;
    const float sig = 1.0f / (1.0f + __expf(-s));

    // broadcast r_i to the n lanes
    const float r = __shfl(sig, srcr, 64);

    // tanh for n lanes: tanh(y) = 1 - 2/(e^{2y}+1)
    const float npre = fmaf(r, preh, prex);
    const float e    = __expf(2.0f * npre);
    const float nt   = 1.0f - 2.0f / (e + 1.0f);

    const float val = (lane < 38) ? sig : nt;

    // gather z_i and n_i onto lane i (lanes 0..18)
    const float z = __shfl(val, srcz, 64);
    const float n = __shfl(val, srcn, 64);
    const float hnew = fmaf(z, h - n, n);   // (1-z)*n + z*h
    h = hnew;  // meaningful on lanes 0..18 only

    // refresh wave-uniform h copy (readlane ignores exec mask)
#pragma unroll
    for (int k = 0; k < HH; ++k) sh[k] = rl(h, k);

    // fused output projection: out[t,b] = h·Wout + bout
    float o = bo;
#pragma unroll
    for (int k = 0; k < HH; ++k) o = fmaf(sh[k], wout[k], o);
    if (lane == 0) out[(size_t)t * NB + b] = o;

    // advance prefetched x
    if (more) {
#pragma unroll
      for (int k = 0; k < HH; ++k) xv[k] = xn[k];
    }
  }
}

extern "C" void kernel_launch(void* const* d_in, const int* in_sizes, int n_in,
                              void* d_out, int out_size, void* d_ws, size_t ws_size,
                              hipStream_t stream) {
  const float* x    = (const float*)d_in[0];
  const float* Wih  = (const float*)d_in[1];
  const float* Whh  = (const float*)d_in[2];
  const float* bih  = (const float*)d_in[3];
  const float* bhh  = (const float*)d_in[4];
  const float* Wout = (const float*)d_in[5];
  const float* bout = (const float*)d_in[6];
  float* out = (float*)d_out;

  gru_fused_kernel<<<dim3(NB), dim3(64), 0, stream>>>(
      x, Wih, Whh, bih, bhh, Wout, bout, out);
}